// Round 11
// baseline (37514.578 us; speedup 1.0000x reference)
//
#include <hip/hip_runtime.h>
#include <math.h>

// WaveRNN autoregressive sampler, persistent kernel, fp32. Round 11:
// round-9 phase order (A:GEMM+nfpoll+cGRU | B:FC1c | C:FC2c | ncpoll |
// D:fGRU | E:FC1f | F:FC2f), with:
//  - NTHR=1024 (16 waves/CU): every latency-exposed sc1 load chain halves
//    (GEMM 56->28 loads/thread, FC2 slices 56->28 floats), 2x waves to hide.
//  - FC2 weights read from GLOBAL (private 36KB/WG slices, L2-resident):
//    removes round-9/10's 1.13e8 LDS bank-conflict cycles (bank =
//    4*(rl+6*kss mod 8) -> 8-way regardless of pad) and frees LDS.
//  - wave0-only polls (round 10), GEMM back in A (round 10's G-move was a
//    serialization loss, -2ms).
// If this lands >=30ms with conflicts gone + occupancy 2x: declare the
// 6-rendezvous LLC-latency floor as the structural ceiling.

#define HALFN  448
#define SIZEN  896
#define RTOT   2688
#define NB     32
#define TSTEPS 1024
#define NWG    224
#define NTHR   1024
#define CONDSTR (RTOT * TSTEPS)
#define FANIN  28   // contributors per batch argmax

// ws float offsets
#define OFF_HID0  0         // [896*32] hid[j*32+b], buffer A
#define OFF_HID1  28672     // buffer B
#define OFF_H1TC  57344     // [32][448] FC1c output, batch-major
#define OFF_H1TF  71680     // [32][448] FC1f output, batch-major
#define OFF_NCP   86016     // 32 x u64 packed coarse argmax
#define OFF_NFP   86080     // 32 x u64 packed fine argmax
#define OFF_DCTRC 86144     // 32 uint done-counters (coarse)
#define OFF_DCTRF 86176     // 32 uint done-counters (fine)
#define OFF_FLAGS 86208     // 256 barrier flags (uint)

typedef unsigned long long u64t;

__device__ __forceinline__ int orig_row(int r) {   // reordered -> original
  int c = r / HALFN, o = r - c * HALFN;
  int oc = (c < 3) ? (2 * c) : (2 * (c - 3) + 1);
  return oc * HALFN + o;
}
__device__ __forceinline__ float sigm(float x) { return 1.0f / (1.0f + expf(-x)); }

__device__ __forceinline__ float gload(const float* p) {
  return __hip_atomic_load(const_cast<float*>(p), __ATOMIC_RELAXED, __HIP_MEMORY_SCOPE_AGENT);
}
__device__ __forceinline__ void gstore(float* p, float v) {
  __hip_atomic_store(p, v, __ATOMIC_RELAXED, __HIP_MEMORY_SCOPE_AGENT);
}
__device__ __forceinline__ u64t gload64(const u64t* p) {
  return __hip_atomic_load(const_cast<u64t*>(p), __ATOMIC_RELAXED, __HIP_MEMORY_SCOPE_AGENT);
}
__device__ __forceinline__ void gstore64(u64t* p, u64t v) {
  __hip_atomic_store(p, v, __ATOMIC_RELAXED, __HIP_MEMORY_SCOPE_AGENT);
}
__device__ __forceinline__ void gmax64(u64t* p, u64t v) {
  __hip_atomic_fetch_max(p, v, __ATOMIC_RELAXED, __HIP_MEMORY_SCOPE_AGENT);
}
__device__ __forceinline__ unsigned ctrload(const unsigned* p) {
  return __hip_atomic_load(const_cast<unsigned*>(p), __ATOMIC_RELAXED, __HIP_MEMORY_SCOPE_AGENT);
}
// order-preserving float->uint (finite inputs)
__device__ __forceinline__ unsigned f2ord(float f) {
  unsigned u = __float_as_uint(f);
  return (u & 0x80000000u) ? ~u : (u | 0x80000000u);
}

struct __align__(16) SM {
  float whh[12][SIZEN];     // 43008 rows {c*448+2w,+1}, c=0..5
  float wc1l[2][HALFN];     // 3584
  float wf1l[2][HALFN];     // 3584
  float red[16][12][32];    // 24576 (16 wave-pair slots at NTHR=1024)
  float condw[12][16][33];  // 25344 16-step cond window [rk][t&15][b]
  float h1c4[4][HALFN];     // 7168 four h1 columns (this WG's batch-group)
  float fcr[4][16][16];     // 4096 FC2 partials [bq][rowlocal][kslice16]
  float flog[4][16];        // 256  FC2 logits
  float hps[6][32];         // coarse hp gates
  float hpfl[6][32];        // fine hp gates
  float chid[2][32];        // persistent c_hid rows 2w,2w+1
  float fhid[2][32];        // persistent f_hid rows 2w,2w+1
  float scvo[32], sfvo[32], sncn[32];
  float ncraw[32], nfraw[32];
  float wcil[2][3][2];      // wci rows {g*448+2w+q}
  float wfil[2][3][3];      // wfi rows
  float bihl[12];
  float bhh_l[12];
};

// wave0-poll grid barrier: release flag, wave 0 polls 224 flags (4/lane),
// one __syncthreads releases the other 15 waves.
__device__ __forceinline__ void gridbar(unsigned* flags, unsigned ep, int& dead) {
  asm volatile("s_waitcnt vmcnt(0)" ::: "memory");
  __syncthreads();
  if (threadIdx.x == 0)
    __hip_atomic_store(&flags[blockIdx.x], ep, __ATOMIC_RELAXED, __HIP_MEMORY_SCOPE_AGENT);
  if (threadIdx.x < 64 && !dead) {
    int it = 0;
    for (;;) {
      int ok = 1;
#pragma unroll
      for (int q = 0; q < 4; q++) {
        int idx = (int)threadIdx.x + q * 64;
        if (idx < NWG) {
          unsigned v = __hip_atomic_load(&flags[idx], __ATOMIC_RELAXED, __HIP_MEMORY_SCOPE_AGENT);
          ok &= (v >= ep) ? 1 : 0;
        }
      }
      if (__all(ok)) break;
      if (++it > (1 << 20)) { dead = 1; break; }   // anti-hang valve
      __builtin_amdgcn_s_sleep(1);
    }
  }
  __syncthreads();
}

// wave0-poll of the 32 per-batch done counters
__device__ __forceinline__ void pollmany(unsigned* arr, unsigned target, int& dead) {
  if (threadIdx.x < 64 && !dead) {
    int it = 0;
    for (;;) {
      int ok = 1;
      if (threadIdx.x < 32)
        ok = (ctrload(&arr[threadIdx.x]) >= target) ? 1 : 0;
      if (__all(ok)) break;
      if (++it > (1 << 20)) { dead = 1; break; }
      __builtin_amdgcn_s_sleep(1);
    }
  }
  __syncthreads();
}

extern "C" __global__ void wavernn_init(float* ws) {
  int i = blockIdx.x * blockDim.x + threadIdx.x;
  int st = gridDim.x * blockDim.x;
  for (int k = i; k < 2 * SIZEN * NB; k += st) ws[k] = 0.0f;     // both hid buffers
  if (i < 64) ((u64t*)(ws + OFF_NCP))[i] = 0ull;                 // ncp+nfp
  if (i < 64) ((unsigned*)(ws + OFF_DCTRC))[i] = 0u;             // dctrc+dctrf
  if (i < 256) ((unsigned*)(ws + OFF_FLAGS))[i] = 0u;
}

extern "C" __global__ void __launch_bounds__(NTHR)
wavernn_persist(const float* __restrict__ cond,
                const float* __restrict__ wci, const float* __restrict__ wfi,
                const float* __restrict__ whh, const float* __restrict__ bih,
                const float* __restrict__ bhh,
                const float* __restrict__ wc1, const float* __restrict__ bc1,
                const float* __restrict__ wc2, const float* __restrict__ bc2,
                const float* __restrict__ wf1, const float* __restrict__ bf1,
                const float* __restrict__ wf2, const float* __restrict__ bf2,
                float* __restrict__ out, float* ws) {
  __shared__ SM sm;

  float* hid0 = ws + OFF_HID0;
  float* hid1 = ws + OFF_HID1;
  float* h1tc = ws + OFF_H1TC;
  float* h1tf = ws + OFF_H1TF;
  u64t*  ncp  = (u64t*)(ws + OFF_NCP);
  u64t*  nfp  = (u64t*)(ws + OFF_NFP);
  unsigned* dctrc = (unsigned*)(ws + OFF_DCTRC);
  unsigned* dctrf = (unsigned*)(ws + OFF_DCTRF);
  unsigned* flags = (unsigned*)(ws + OFF_FLAGS);

  const int w = blockIdx.x, tid = threadIdx.x;
  const int b = tid & 31, ks = tid >> 5;       // 32 k-slices x 32 batch
  const int rb = w >> 3, bg = w & 7;           // FC2 rowblock x batch-group
  const int fc2start = (rb < 4) ? rb * 10 : 40 + (rb - 4) * 9;
  const int fc2len   = (rb < 4) ? 10 : 9;
  unsigned ep = 0;
  int dead = 0;

  // ---------- one-time LDS staging ----------
#pragma unroll
  for (int rr = 0; rr < 12; rr++) {
    int R = (rr >> 1) * HALFN + 2 * w + (rr & 1);
    const float* src = whh + (size_t)orig_row(R) * SIZEN;
    for (int k = tid * 4; k < SIZEN; k += NTHR * 4)
      *(float4*)&sm.whh[rr][k] = *(const float4*)&src[k];
  }
  if (tid < 12) sm.bhh_l[tid] = bhh[orig_row((tid >> 1) * HALFN + 2 * w + (tid & 1))];
  for (int k = tid * 4; k < HALFN; k += NTHR * 4) {
    *(float4*)&sm.wc1l[0][k] = *(const float4*)&wc1[(size_t)(2 * w) * HALFN + k];
    *(float4*)&sm.wc1l[1][k] = *(const float4*)&wc1[(size_t)(2 * w + 1) * HALFN + k];
    *(float4*)&sm.wf1l[0][k] = *(const float4*)&wf1[(size_t)(2 * w) * HALFN + k];
    *(float4*)&sm.wf1l[1][k] = *(const float4*)&wf1[(size_t)(2 * w + 1) * HALFN + k];
  }
  if (tid < 12) {   // bih slice: rk -> global row R
    int rk = tid;
    int R = ((rk >= 6) ? HALFN : 0) + ((rk % 6) >> 1) * SIZEN + 2 * w + (rk & 1);
    sm.bihl[rk] = bih[R];
  }
  if (tid < 2) {    // wci/wfi slices
    int j = 2 * w + tid;
#pragma unroll
    for (int g = 0; g < 3; g++) {
      sm.wcil[tid][g][0] = wci[(g * HALFN + j) * 2 + 0];
      sm.wcil[tid][g][1] = wci[(g * HALFN + j) * 2 + 1];
      sm.wfil[tid][g][0] = wfi[(g * HALFN + j) * 3 + 0];
      sm.wfil[tid][g][1] = wfi[(g * HALFN + j) * 3 + 1];
      sm.wfil[tid][g][2] = wfi[(g * HALFN + j) * 3 + 2];
    }
  }
  if (tid < 64) { sm.chid[tid >> 5][tid & 31] = 0.0f; sm.fhid[tid >> 5][tid & 31] = 0.0f; }
  if (tid < 32) { sm.scvo[tid] = 128.0f * (2.0f / 255.0f) - 1.0f; sm.sfvo[tid] = -1.0f; }
  __syncthreads();

  for (int t = 0; t < TSTEPS; ++t) {
    const float* hprev = (t & 1) ? hid0 : hid1;
    float*       hcur  = (t & 1) ? hid1 : hid0;
    const int tt = t & 15;

    // ========== A: [cond prefetch] + GEMM + nf-poll + coarse GRU ==========
    {
      if (tt == 0) {   // 16-step cond window -> LDS
        for (int idx = tid; idx < 1536; idx += NTHR) {
          int rk = idx >> 7, rem = idx & 127;
          int bb = rem >> 2, part = rem & 3;
          int R = ((rk >= 6) ? HALFN : 0) + ((rk % 6) >> 1) * SIZEN + 2 * w + (rk & 1);
          float4 v = *(const float4*)&cond[(size_t)bb * CONDSTR + (size_t)R * TSTEPS + t + part * 4];
          sm.condw[rk][part * 4 + 0][bb] = v.x;
          sm.condw[rk][part * 4 + 1][bb] = v.y;
          sm.condw[rk][part * 4 + 2][bb] = v.z;
          sm.condw[rk][part * 4 + 3][bb] = v.w;
        }
      }

      // GEMM: 32 k-slices of 28, 12 rows
      float acc[12];
#pragma unroll
      for (int rr = 0; rr < 12; rr++) acc[rr] = 0.0f;
      const int k0 = ks * 28;
      const float* hcol = hprev + b;
#pragma unroll
      for (int k = k0; k < k0 + 28; k += 4) {
        float h0 = gload(&hcol[(k + 0) * 32]), h1v = gload(&hcol[(k + 1) * 32]);
        float h2 = gload(&hcol[(k + 2) * 32]), h3  = gload(&hcol[(k + 3) * 32]);
#pragma unroll
        for (int rr = 0; rr < 12; rr++) {
          const float4 wv = *(const float4*)&sm.whh[rr][k];
          acc[rr] = fmaf(wv.x, h0, fmaf(wv.y, h1v, fmaf(wv.z, h2, fmaf(wv.w, h3, acc[rr]))));
        }
      }
#pragma unroll
      for (int rr = 0; rr < 12; rr++) acc[rr] += __shfl_xor(acc[rr], 32);
      __syncthreads();   // red reuse fence
      if ((tid & 32) == 0) {
        int slot = ks >> 1;   // 0..15
#pragma unroll
        for (int rr = 0; rr < 12; rr++) sm.red[slot][rr][b] = acc[rr];
      }
      __syncthreads();
      if (tid < 384) {
        int rr = tid >> 5, bb = tid & 31;
        float s = sm.bhh_l[rr];
#pragma unroll
        for (int kk = 0; kk < 16; kk++) s += sm.red[kk][rr][bb];
        if (rr < 6) sm.hps[rr][bb] = s;
        else        sm.hpfl[rr - 6][bb] = s;
      }
      // nf(t-1): poll 32 per-batch done-counters
      if (t > 0) {
        pollmany(dctrf, FANIN * (unsigned)t, dead);
        if (tid < 32) {
          u64t p = gload64(&nfp[tid]);
          unsigned nf = 0xFFFFFFFFu - (unsigned)(p & 0xFFFFFFFFull);
          sm.sfvo[tid] = (float)nf * (2.0f / 255.0f) - 1.0f;
          sm.nfraw[tid] = (float)nf;
        }
      }
      __syncthreads();
      if (t > 0 && w < 32 && tid == 64)
        out[32768 + (size_t)w * TSTEPS + (t - 1)] = sm.nfraw[w];
      // coarse GRU for j = 2w, 2w+1 (all LDS-local)
      if (tid < 64) {
        int q = tid >> 5, bb = tid & 31;
        float sc = sm.scvo[bb], sf = sm.sfvo[bb];
        float ipr = sm.wcil[q][0][0] * sc + sm.wcil[q][0][1] * sf + sm.condw[0 + q][tt][bb] + sm.bihl[0 + q];
        float ipu = sm.wcil[q][1][0] * sc + sm.wcil[q][1][1] * sf + sm.condw[2 + q][tt][bb] + sm.bihl[2 + q];
        float ipe = sm.wcil[q][2][0] * sc + sm.wcil[q][2][1] * sf + sm.condw[4 + q][tt][bb] + sm.bihl[4 + q];
        float r = sigm(sm.hps[0 + q][bb] + ipr);
        float u = sigm(sm.hps[2 + q][bb] + ipu);
        float e = tanhf(fmaf(r, sm.hps[4 + q][bb], ipe));
        float hnew = u * sm.chid[q][bb] + (1.0f - u) * e;
        sm.chid[q][bb] = hnew;
        gstore(&hcur[(size_t)(2 * w + q) * 32 + bb], hnew);
      }
    }
    gridbar(flags, ++ep, dead);                       // bar1: h_c ready

    // ========== B: FC1 coarse (rows 2w,2w+1) -> h1tc batch-major ==========
    {
      float a0 = 0.0f, a1 = 0.0f;
      if (ks < 16) {
        const int k0 = ks * 28;
        const float* hcc = hcur + b;
#pragma unroll
        for (int k = k0; k < k0 + 28; k += 4) {
          float h0 = gload(&hcc[(k + 0) * 32]), h1v = gload(&hcc[(k + 1) * 32]);
          float h2 = gload(&hcc[(k + 2) * 32]), h3  = gload(&hcc[(k + 3) * 32]);
          float4 v0 = *(const float4*)&sm.wc1l[0][k];
          a0 = fmaf(v0.x, h0, fmaf(v0.y, h1v, fmaf(v0.z, h2, fmaf(v0.w, h3, a0))));
          float4 v1 = *(const float4*)&sm.wc1l[1][k];
          a1 = fmaf(v1.x, h0, fmaf(v1.y, h1v, fmaf(v1.z, h2, fmaf(v1.w, h3, a1))));
        }
        a0 += __shfl_xor(a0, 32); a1 += __shfl_xor(a1, 32);
      }
      __syncthreads();
      if (ks < 16 && (tid & 32) == 0) { sm.red[ks >> 1][0][b] = a0; sm.red[ks >> 1][1][b] = a1; }
      if (w < 32 && tid == 512) gstore64(&nfp[w], 0ull);   // reset (consumed in A)
      __syncthreads();
      if (tid < 64) {
        int rr = tid >> 5, bb = tid & 31;
        float s = bc1[2 * w + rr];
#pragma unroll
        for (int kk = 0; kk < 8; kk++) s += sm.red[kk][rr][bb];
        gstore(&h1tc[(size_t)bb * HALFN + 2 * w + rr], fmaxf(s, 0.0f));
      }
    }
    gridbar(flags, ++ep, dead);                       // bar2: h1c ready

    // ========== C: FC2 coarse rowblock x batch-group (weights from L2) ==========
    {
      for (int i = tid; i < 4 * HALFN; i += NTHR)
        sm.h1c4[i / HALFN][i % HALFN] = gload(&h1tc[(size_t)(4 * bg + i / HALFN) * HALFN + (i % HALFN)]);
      __syncthreads();
      {
        int bq = tid >> 8, rl = (tid >> 4) & 15, kss = tid & 15;
        if (rl < fc2len) {
          const float* wrow = wc2 + (size_t)(fc2start + rl) * HALFN;
          const float* hcol = sm.h1c4[bq];
          float a = 0.0f;
          int kk0 = kss * 28;
#pragma unroll
          for (int k = kk0; k < kk0 + 28; k += 4) {
            float4 wv = *(const float4*)&wrow[k];
            float4 hv = *(const float4*)&hcol[k];
            a = fmaf(wv.x, hv.x, fmaf(wv.y, hv.y, fmaf(wv.z, hv.z, fmaf(wv.w, hv.w, a))));
          }
          sm.fcr[bq][rl][kss] = a;
        }
      }
      __syncthreads();
      if (tid < 64) {
        int bq = tid >> 4, rl = tid & 15;
        if (rl < fc2len) {
          float s = bc2[fc2start + rl];
#pragma unroll
          for (int q = 0; q < 16; q++) s += sm.fcr[bq][rl][q];
          sm.flog[bq][rl] = s;
        }
      }
      __syncthreads();
      if (tid < 4) {
        int bq = tid;
        float bv = sm.flog[bq][0]; int bi = 0;
        for (int rl = 1; rl < fc2len; rl++) {
          float x = sm.flog[bq][rl];
          if (x > bv) { bv = x; bi = rl; }
        }
        u64t pack = ((u64t)f2ord(bv) << 32) | (u64t)(0xFFFFFFFFu - (unsigned)(fc2start + bi));
        gmax64(&ncp[4 * bg + bq], pack);
        asm volatile("s_waitcnt vmcnt(0)" ::: "memory");
        __hip_atomic_fetch_add(&dctrc[4 * bg + bq], 1u, __ATOMIC_RELAXED, __HIP_MEMORY_SCOPE_AGENT);
      }
    }
    pollmany(dctrc, FANIN * (unsigned)(t + 1), dead);   // nc ready

    // ========== D: fine GRU (all WGs, j=2w,2w+1) ==========
    {
      if (tid < 32) {
        u64t p = gload64(&ncp[tid]);
        unsigned nc = 0xFFFFFFFFu - (unsigned)(p & 0xFFFFFFFFull);
        sm.sncn[tid] = (float)nc * (2.0f / 255.0f) - 1.0f;
        sm.ncraw[tid] = (float)nc;
      }
      __syncthreads();
      if (w < 32 && tid == 64) out[(size_t)w * TSTEPS + t] = sm.ncraw[w];
      if (tid < 64) {
        int q = tid >> 5, bb = tid & 31;
        float sc = sm.scvo[bb], sf = sm.sfvo[bb], snc = sm.sncn[bb];
        float ipr = sm.wfil[q][0][0] * sc + sm.wfil[q][0][1] * sf + sm.wfil[q][0][2] * snc
                  + sm.condw[6 + q][tt][bb] + sm.bihl[6 + q];
        float ipu = sm.wfil[q][1][0] * sc + sm.wfil[q][1][1] * sf + sm.wfil[q][1][2] * snc
                  + sm.condw[8 + q][tt][bb] + sm.bihl[8 + q];
        float ipe = sm.wfil[q][2][0] * sc + sm.wfil[q][2][1] * sf + sm.wfil[q][2][2] * snc
                  + sm.condw[10 + q][tt][bb] + sm.bihl[10 + q];
        float r = sigm(sm.hpfl[0 + q][bb] + ipr);
        float u = sigm(sm.hpfl[2 + q][bb] + ipu);
        float e = tanhf(fmaf(r, sm.hpfl[4 + q][bb], ipe));
        float hnew = u * sm.fhid[q][bb] + (1.0f - u) * e;
        sm.fhid[q][bb] = hnew;
        gstore(&hcur[(size_t)(HALFN + 2 * w + q) * 32 + bb], hnew);
      }
      __syncthreads();
      if (tid < 32) sm.scvo[tid] = sm.sncn[tid];   // commit nc(t)
    }
    gridbar(flags, ++ep, dead);                       // bar3: h_f ready

    // ========== E: FC1 fine (rows 2w,2w+1) -> h1tf batch-major ==========
    {
      float a0 = 0.0f, a1 = 0.0f;
      if (ks < 16) {
        const int k0 = ks * 28;
        const float* hff = hcur + HALFN * 32 + b;
#pragma unroll
        for (int k = k0; k < k0 + 28; k += 4) {
          float h0 = gload(&hff[(k + 0) * 32]), h1v = gload(&hff[(k + 1) * 32]);
          float h2 = gload(&hff[(k + 2) * 32]), h3  = gload(&hff[(k + 3) * 32]);
          float4 v0 = *(const float4*)&sm.wf1l[0][k];
          a0 = fmaf(v0.x, h0, fmaf(v0.y, h1v, fmaf(v0.z, h2, fmaf(v0.w, h3, a0))));
          float4 v1 = *(const float4*)&sm.wf1l[1][k];
          a1 = fmaf(v1.x, h0, fmaf(v1.y, h1v, fmaf(v1.z, h2, fmaf(v1.w, h3, a1))));
        }
        a0 += __shfl_xor(a0, 32); a1 += __shfl_xor(a1, 32);
      }
      __syncthreads();
      if (ks < 16 && (tid & 32) == 0) { sm.red[ks >> 1][0][b] = a0; sm.red[ks >> 1][1][b] = a1; }
      if (w < 32 && tid == 512) gstore64(&ncp[w], 0ull);   // reset (consumed in D)
      __syncthreads();
      if (tid < 64) {
        int rr = tid >> 5, bb = tid & 31;
        float s = bf1[2 * w + rr];
#pragma unroll
        for (int kk = 0; kk < 8; kk++) s += sm.red[kk][rr][bb];
        gstore(&h1tf[(size_t)bb * HALFN + 2 * w + rr], fmaxf(s, 0.0f));
      }
    }
    gridbar(flags, ++ep, dead);                       // bar4: h1f ready

    // ========== F: FC2 fine (weights from L2) — nf consumed at A(t+1) ==========
    {
      for (int i = tid; i < 4 * HALFN; i += NTHR)
        sm.h1c4[i / HALFN][i % HALFN] = gload(&h1tf[(size_t)(4 * bg + i / HALFN) * HALFN + (i % HALFN)]);
      __syncthreads();
      {
        int bq = tid >> 8, rl = (tid >> 4) & 15, kss = tid & 15;
        if (rl < fc2len) {
          const float* wrow = wf2 + (size_t)(fc2start + rl) * HALFN;
          const float* hcol = sm.h1c4[bq];
          float a = 0.0f;
          int kk0 = kss * 28;
#pragma unroll
          for (int k = kk0; k < kk0 + 28; k += 4) {
            float4 wv = *(const float4*)&wrow[k];
            float4 hv = *(const float4*)&hcol[k];
            a = fmaf(wv.x, hv.x, fmaf(wv.y, hv.y, fmaf(wv.z, hv.z, fmaf(wv.w, hv.w, a))));
          }
          sm.fcr[bq][rl][kss] = a;
        }
      }
      __syncthreads();
      if (tid < 64) {
        int bq = tid >> 4, rl = tid & 15;
        if (rl < fc2len) {
          float s = bf2[fc2start + rl];
#pragma unroll
          for (int q = 0; q < 16; q++) s += sm.fcr[bq][rl][q];
          sm.flog[bq][rl] = s;
        }
      }
      __syncthreads();
      if (tid < 4) {
        int bq = tid;
        float bv = sm.flog[bq][0]; int bi = 0;
        for (int rl = 1; rl < fc2len; rl++) {
          float x = sm.flog[bq][rl];
          if (x > bv) { bv = x; bi = rl; }
        }
        u64t pack = ((u64t)f2ord(bv) << 32) | (u64t)(0xFFFFFFFFu - (unsigned)(fc2start + bi));
        gmax64(&nfp[4 * bg + bq], pack);
        asm volatile("s_waitcnt vmcnt(0)" ::: "memory");
        __hip_atomic_fetch_add(&dctrf[4 * bg + bq], 1u, __ATOMIC_RELAXED, __HIP_MEMORY_SCOPE_AGENT);
      }
    }
    // no barrier: all WGs proceed into next A; nf consumed via poll there
  }

  // ===== epilogue: nf(1023) + final hidden =====
  pollmany(dctrf, FANIN * (unsigned)TSTEPS, dead);
  if (w < 32 && tid == 0) {
    u64t p = gload64(&nfp[w]);
    unsigned nf = 0xFFFFFFFFu - (unsigned)(p & 0xFFFFFFFFull);
    out[32768 + (size_t)w * TSTEPS + (TSTEPS - 1)] = (float)nf;
  }
  if (tid < 64) {
    int q = tid >> 5, bb = tid & 31;
    out[65536 + (size_t)(2 * w + q) * 32 + bb]         = sm.chid[q][bb];
    out[65536 + (size_t)(HALFN + 2 * w + q) * 32 + bb] = sm.fhid[q][bb];
  }
}

extern "C" void kernel_launch(void* const* d_in, const int* in_sizes, int n_in,
                              void* d_out, int out_size, void* d_ws, size_t ws_size,
                              hipStream_t stream) {
  const float* cond = (const float*)d_in[0];
  const float* wci  = (const float*)d_in[1];
  const float* wfi  = (const float*)d_in[2];
  const float* whh  = (const float*)d_in[3];
  const float* bih  = (const float*)d_in[4];
  const float* bhh  = (const float*)d_in[5];
  const float* wc1  = (const float*)d_in[6];
  const float* bc1  = (const float*)d_in[7];
  const float* wc2  = (const float*)d_in[8];
  const float* bc2  = (const float*)d_in[9];
  const float* wf1  = (const float*)d_in[10];
  const float* bf1  = (const float*)d_in[11];
  const float* wf2  = (const float*)d_in[12];
  const float* bf2  = (const float*)d_in[13];
  float* out = (float*)d_out;
  float* ws  = (float*)d_ws;

  hipLaunchKernelGGL(wavernn_init, dim3(64), dim3(256), 0, stream, ws);
  hipLaunchKernelGGL(wavernn_persist, dim3(NWG), dim3(NTHR), 0, stream,
                     cond, wci, wfi, whh, bih, bhh,
                     wc1, bc1, wc2, bc2, wf1, bf1, wf2, bf2, out, ws);
}

// Round 12
// 30898.547 us; speedup vs baseline: 1.2141x; 1.2141x over previous
//
#include <hip/hip_runtime.h>
#include <math.h>

// WaveRNN autoregressive sampler, persistent kernel, fp32. Round 12:
// EXACT round-8 structure (best measured: 31.1 ms) with ONE isolated change:
// wave0-only polling in gridbar/pollctr (7 waves park at one __syncthreads;
// wave 0 spins with __all) instead of all-8-wave __syncthreads_and per poll
// iteration. Rounds 9/10/11 (FC2-spread / G-move / 1024thr) all regressed;
// this isolates the poll mechanics variable against the 31.1 baseline.
// Phases: A: condwin+GEMM+nfpoll+cGRU | B: FC1c | C: FC2c+argmax (heads) |
// ncpoll | D: fGRU (distributed) | E: FC1f | F: FC2f (heads, overlaps next A).
// Weights all LDS (whh 12 rows, wc1/wf1 2 rows, wc2/wf2 8 rows on heads);
// cond in 16-step LDS windows; state via relaxed AGENT atomics (LLC).

#define HALFN  448
#define SIZEN  896
#define RTOT   2688
#define NB     32
#define TSTEPS 1024
#define NWG    224
#define NTHR   512
#define CONDSTR (RTOT * TSTEPS)

// ws float offsets
#define OFF_HID0  0         // [896*32] hid[j*32+b], buffer A
#define OFF_HID1  28672     // buffer B
#define OFF_H1GC  57344     // [448*32] FC1c output
#define OFF_H1GF  71680     // [448*32] FC1f output
#define OFF_NCP   86016     // 32 x u64 packed coarse argmax
#define OFF_NFP   86080     // 32 x u64 packed fine argmax
#define OFF_CTR   86144     // [0]=ncCtr [1]=nfCtr (uint)
#define OFF_FLAGS 86400     // 256 barrier flags (uint)

typedef unsigned long long u64t;

__device__ __forceinline__ int orig_row(int r) {   // reordered -> original
  int c = r / HALFN, o = r - c * HALFN;
  int oc = (c < 3) ? (2 * c) : (2 * (c - 3) + 1);
  return oc * HALFN + o;
}
__device__ __forceinline__ float sigm(float x) { return 1.0f / (1.0f + expf(-x)); }

__device__ __forceinline__ float gload(const float* p) {
  return __hip_atomic_load(const_cast<float*>(p), __ATOMIC_RELAXED, __HIP_MEMORY_SCOPE_AGENT);
}
__device__ __forceinline__ void gstore(float* p, float v) {
  __hip_atomic_store(p, v, __ATOMIC_RELAXED, __HIP_MEMORY_SCOPE_AGENT);
}
__device__ __forceinline__ u64t gload64(const u64t* p) {
  return __hip_atomic_load(const_cast<u64t*>(p), __ATOMIC_RELAXED, __HIP_MEMORY_SCOPE_AGENT);
}
__device__ __forceinline__ void gstore64(u64t* p, u64t v) {
  __hip_atomic_store(p, v, __ATOMIC_RELAXED, __HIP_MEMORY_SCOPE_AGENT);
}
__device__ __forceinline__ void gmax64(u64t* p, u64t v) {
  __hip_atomic_fetch_max(p, v, __ATOMIC_RELAXED, __HIP_MEMORY_SCOPE_AGENT);
}
__device__ __forceinline__ unsigned ctrload(const unsigned* p) {
  return __hip_atomic_load(const_cast<unsigned*>(p), __ATOMIC_RELAXED, __HIP_MEMORY_SCOPE_AGENT);
}
// order-preserving float->uint (finite inputs)
__device__ __forceinline__ unsigned f2ord(float f) {
  unsigned u = __float_as_uint(f);
  return (u & 0x80000000u) ? ~u : (u | 0x80000000u);
}

struct __align__(16) SM {
  float whh[12][SIZEN];     // 43008 rows {c*448+2w, +1}, c=0..5
  float wc1l[2][HALFN];     // 3584
  float wf1l[2][HALFN];     // 3584
  float wc2l[8][HALFN];     // 14336 (heads)
  float wf2l[8][HALFN];     // 14336 (heads)
  float red[8][12][32];     // 12288
  float condw[12][16][33];  // 25344: 16-step cond window, [rk][t&15][b]
  float hps[6][32];         // coarse hp gates (r0,r1,u0,u1,e0,e1)
  float hpfl[6][32];        // fine hp gates
  float chid[2][32];        // persistent c_hid rows 2w,2w+1
  float fhid[2][32];        // persistent f_hid rows 2w,2w+1
  float scvo[32];           // scale(nc(t-1))
  float sfvo[32];           // scale(nf(t-1))
  float sncn[32];           // scale(nc(t))
  float logit8[8][32];
  float wcil[2][3][2];      // wci rows {g*448+2w+q}
  float wfil[2][3][3];      // wfi rows {g*448+2w+q}
  float bihl[12];           // bih[R(rk)]
  float bhh_l[12];
};

// wave0-poll grid barrier: all waves drain+sync, tid0 releases flag, wave 0
// polls 224 flags (4/lane) with __all; one final __syncthreads releases all.
__device__ __forceinline__ void gridbar(unsigned* flags, unsigned ep, int& dead) {
  asm volatile("s_waitcnt vmcnt(0)" ::: "memory");
  __syncthreads();
  if (threadIdx.x == 0)
    __hip_atomic_store(&flags[blockIdx.x], ep, __ATOMIC_RELAXED, __HIP_MEMORY_SCOPE_AGENT);
  if (threadIdx.x < 64 && !dead) {
    int it = 0;
    for (;;) {
      int ok = 1;
#pragma unroll
      for (int q = 0; q < 4; q++) {
        int idx = (int)threadIdx.x + q * 64;
        if (idx < NWG) {
          unsigned v = __hip_atomic_load(&flags[idx], __ATOMIC_RELAXED, __HIP_MEMORY_SCOPE_AGENT);
          ok &= (v >= ep) ? 1 : 0;
        }
      }
      if (__all(ok)) break;
      if (++it > (1 << 20)) { dead = 1; break; }   // anti-hang valve
      __builtin_amdgcn_s_sleep(1);
    }
  }
  __syncthreads();
}

// wave0-poll of a single done-counter
__device__ __forceinline__ void pollctr(unsigned* ctr, unsigned target, int& dead) {
  if (threadIdx.x < 64 && !dead) {
    int it = 0;
    for (;;) {
      unsigned v = ctrload(ctr);
      if (__all(v >= target)) break;
      if (++it > (1 << 20)) { dead = 1; break; }
      __builtin_amdgcn_s_sleep(1);
    }
  }
  __syncthreads();
}

extern "C" __global__ void wavernn_init(float* ws) {
  int i = blockIdx.x * blockDim.x + threadIdx.x;
  int st = gridDim.x * blockDim.x;
  for (int k = i; k < 2 * SIZEN * NB; k += st) ws[k] = 0.0f;     // both hid buffers
  if (i < 64) ((u64t*)(ws + OFF_NCP))[i] = 0ull;                 // ncp+nfp
  if (i < 2) ((unsigned*)(ws + OFF_CTR))[i] = 0u;
  if (i < 256) ((unsigned*)(ws + OFF_FLAGS))[i] = 0u;
}

extern "C" __global__ void __launch_bounds__(NTHR)
wavernn_persist(const float* __restrict__ cond,
                const float* __restrict__ wci, const float* __restrict__ wfi,
                const float* __restrict__ whh, const float* __restrict__ bih,
                const float* __restrict__ bhh,
                const float* __restrict__ wc1, const float* __restrict__ bc1,
                const float* __restrict__ wc2, const float* __restrict__ bc2,
                const float* __restrict__ wf1, const float* __restrict__ bf1,
                const float* __restrict__ wf2, const float* __restrict__ bf2,
                float* __restrict__ out, float* ws) {
  __shared__ SM sm;

  float* hid0 = ws + OFF_HID0;
  float* hid1 = ws + OFF_HID1;
  float* h1gc = ws + OFF_H1GC;
  float* h1gf = ws + OFF_H1GF;
  u64t*  ncp  = (u64t*)(ws + OFF_NCP);
  u64t*  nfp  = (u64t*)(ws + OFF_NFP);
  unsigned* ctr = (unsigned*)(ws + OFF_CTR);   // [0]=nc [1]=nf
  unsigned* flags = (unsigned*)(ws + OFF_FLAGS);

  const int w = blockIdx.x, tid = threadIdx.x;
  const int b = tid & 31, ks = tid >> 5;     // 16 k-slices x 32 batch
  const bool isHead = (w < NB);
  unsigned ep = 0;
  int dead = 0;

  // ---------- one-time LDS staging ----------
#pragma unroll
  for (int rr = 0; rr < 12; rr++) {
    int R = (rr >> 1) * HALFN + 2 * w + (rr & 1);
    const float* src = whh + (size_t)orig_row(R) * SIZEN;
    for (int k = tid * 4; k < SIZEN; k += NTHR * 4)
      *(float4*)&sm.whh[rr][k] = *(const float4*)&src[k];
  }
  if (tid < 12) sm.bhh_l[tid] = bhh[orig_row((tid >> 1) * HALFN + 2 * w + (tid & 1))];
  for (int k = tid * 4; k < HALFN; k += NTHR * 4) {
    *(float4*)&sm.wc1l[0][k] = *(const float4*)&wc1[(size_t)(2 * w) * HALFN + k];
    *(float4*)&sm.wc1l[1][k] = *(const float4*)&wc1[(size_t)(2 * w + 1) * HALFN + k];
    *(float4*)&sm.wf1l[0][k] = *(const float4*)&wf1[(size_t)(2 * w) * HALFN + k];
    *(float4*)&sm.wf1l[1][k] = *(const float4*)&wf1[(size_t)(2 * w + 1) * HALFN + k];
  }
  if (isHead) {
#pragma unroll
    for (int rr = 0; rr < 8; rr++) {
      for (int k = tid * 4; k < HALFN; k += NTHR * 4) {
        *(float4*)&sm.wc2l[rr][k] = *(const float4*)&wc2[(size_t)(w * 8 + rr) * HALFN + k];
        *(float4*)&sm.wf2l[rr][k] = *(const float4*)&wf2[(size_t)(w * 8 + rr) * HALFN + k];
      }
    }
  }
  if (tid < 12) {   // bih slice: rk -> global row R
    int rk = tid;
    int R = ((rk >= 6) ? HALFN : 0) + ((rk % 6) >> 1) * SIZEN + 2 * w + (rk & 1);
    sm.bihl[rk] = bih[R];
  }
  if (tid < 2) {    // wci/wfi slices (rows g*448 + j)
    int j = 2 * w + tid;
#pragma unroll
    for (int g = 0; g < 3; g++) {
      sm.wcil[tid][g][0] = wci[(g * HALFN + j) * 2 + 0];
      sm.wcil[tid][g][1] = wci[(g * HALFN + j) * 2 + 1];
      sm.wfil[tid][g][0] = wfi[(g * HALFN + j) * 3 + 0];
      sm.wfil[tid][g][1] = wfi[(g * HALFN + j) * 3 + 1];
      sm.wfil[tid][g][2] = wfi[(g * HALFN + j) * 3 + 2];
    }
  }
  if (tid < 64) { sm.chid[tid >> 5][tid & 31] = 0.0f; sm.fhid[tid >> 5][tid & 31] = 0.0f; }
  if (tid < 32) { sm.scvo[tid] = 128.0f * (2.0f / 255.0f) - 1.0f; sm.sfvo[tid] = -1.0f; }
  __syncthreads();

  for (int t = 0; t < TSTEPS; ++t) {
    const float* hprev = (t & 1) ? hid0 : hid1;
    float*       hcur  = (t & 1) ? hid1 : hid0;
    const int tt = t & 15;

    // ========== A: [cond prefetch] + GEMM + nf-poll + coarse GRU ==========
    {
      // 16-step cond window -> LDS (12 rows x 32 b x 16 t = 24 KB)
      if (tt == 0) {
        for (int idx = tid; idx < 1536; idx += NTHR) {
          int rk = idx >> 7, rem = idx & 127;
          int bb = rem >> 2, part = rem & 3;
          int R = ((rk >= 6) ? HALFN : 0) + ((rk % 6) >> 1) * SIZEN + 2 * w + (rk & 1);
          float4 v = *(const float4*)&cond[(size_t)bb * CONDSTR + (size_t)R * TSTEPS + t + part * 4];
          sm.condw[rk][part * 4 + 0][bb] = v.x;
          sm.condw[rk][part * 4 + 1][bb] = v.y;
          sm.condw[rk][part * 4 + 2][bb] = v.z;
          sm.condw[rk][part * 4 + 3][bb] = v.w;
        }
      }

      float acc[12];
#pragma unroll
      for (int rr = 0; rr < 12; rr++) acc[rr] = 0.0f;
      const int k0 = ks * 56;
      const float* hcol = hprev + b;
#pragma unroll 2
      for (int k = k0; k < k0 + 56; k += 4) {
        float h0 = gload(&hcol[(k + 0) * 32]), h1v = gload(&hcol[(k + 1) * 32]);
        float h2 = gload(&hcol[(k + 2) * 32]), h3  = gload(&hcol[(k + 3) * 32]);
#pragma unroll
        for (int rr = 0; rr < 12; rr++) {
          const float4 wv = *(const float4*)&sm.whh[rr][k];
          acc[rr] = fmaf(wv.x, h0, fmaf(wv.y, h1v, fmaf(wv.z, h2, fmaf(wv.w, h3, acc[rr]))));
        }
      }
#pragma unroll
      for (int rr = 0; rr < 12; rr++) acc[rr] += __shfl_xor(acc[rr], 32);
      __syncthreads();   // red reuse fence (covers heads' F-phase reads)
      if ((tid & 32) == 0) {
        int slot = ks >> 1;
#pragma unroll
        for (int rr = 0; rr < 12; rr++) sm.red[slot][rr][b] = acc[rr];
      }
      __syncthreads();
      if (tid < 384) {
        int rr = tid >> 5, bb = tid & 31;
        float s = sm.bhh_l[rr];
#pragma unroll
        for (int kk = 0; kk < 8; kk++) s += sm.red[kk][rr][bb];
        if (rr < 6) sm.hps[rr][bb] = s;
        else        sm.hpfl[rr - 6][bb] = s;
      }
      // nf(t-1): single-address poll (heads computed it overlapped with our GEMM)
      if (t > 0) {
        pollctr(&ctr[1], 32u * (unsigned)t, dead);
        if (tid < 32) {
          u64t p = gload64(&nfp[tid]);
          unsigned nf = 0xFFFFFFFFu - (unsigned)(p & 0xFFFFFFFFull);
          sm.sfvo[tid] = (float)nf * (2.0f / 255.0f) - 1.0f;
          if (isHead && tid == w) out[32768 + (size_t)w * TSTEPS + (t - 1)] = (float)nf;
        }
      }
      __syncthreads();
      // coarse GRU for j = 2w, 2w+1 (everything LDS-local)
      if (tid < 64) {
        int q = tid >> 5, bb = tid & 31;
        float sc = sm.scvo[bb], sf = sm.sfvo[bb];
        float ipr = sm.wcil[q][0][0] * sc + sm.wcil[q][0][1] * sf + sm.condw[0 + q][tt][bb] + sm.bihl[0 + q];
        float ipu = sm.wcil[q][1][0] * sc + sm.wcil[q][1][1] * sf + sm.condw[2 + q][tt][bb] + sm.bihl[2 + q];
        float ipe = sm.wcil[q][2][0] * sc + sm.wcil[q][2][1] * sf + sm.condw[4 + q][tt][bb] + sm.bihl[4 + q];
        float r = sigm(sm.hps[0 + q][bb] + ipr);
        float u = sigm(sm.hps[2 + q][bb] + ipu);
        float e = tanhf(fmaf(r, sm.hps[4 + q][bb], ipe));
        float hnew = u * sm.chid[q][bb] + (1.0f - u) * e;
        sm.chid[q][bb] = hnew;
        gstore(&hcur[(size_t)(2 * w + q) * 32 + bb], hnew);
      }
    }
    gridbar(flags, ++ep, dead);                       // bar1: h_c ready

    // ========== B: FC1 coarse (rows 2w,2w+1) ==========
    {
      const int k0 = ks * 28;
      float a0 = 0.0f, a1 = 0.0f;
      const float* hcc = hcur + b;
#pragma unroll
      for (int k = k0; k < k0 + 28; k += 4) {
        float h0 = gload(&hcc[(k + 0) * 32]), h1v = gload(&hcc[(k + 1) * 32]);
        float h2 = gload(&hcc[(k + 2) * 32]), h3  = gload(&hcc[(k + 3) * 32]);
        float4 v0 = *(const float4*)&sm.wc1l[0][k];
        a0 = fmaf(v0.x, h0, fmaf(v0.y, h1v, fmaf(v0.z, h2, fmaf(v0.w, h3, a0))));
        float4 v1 = *(const float4*)&sm.wc1l[1][k];
        a1 = fmaf(v1.x, h0, fmaf(v1.y, h1v, fmaf(v1.z, h2, fmaf(v1.w, h3, a1))));
      }
      a0 += __shfl_xor(a0, 32); a1 += __shfl_xor(a1, 32);
      __syncthreads();
      if ((tid & 32) == 0) { sm.red[ks >> 1][0][b] = a0; sm.red[ks >> 1][1][b] = a1; }
      if (isHead && tid == 256) gstore64(&nfp[w], 0ull);   // reset this step's pack
      __syncthreads();
      if (tid < 64) {
        int rr = tid >> 5, bb = tid & 31;
        float s = bc1[2 * w + rr];
#pragma unroll
        for (int kk = 0; kk < 8; kk++) s += sm.red[kk][rr][bb];
        gstore(&h1gc[(size_t)(2 * w + rr) * 32 + bb], fmaxf(s, 0.0f));
      }
    }
    gridbar(flags, ++ep, dead);                       // bar2: h1c ready

    // ========== C: FC2 coarse (heads) -> packed atomicMax + counter ==========
    if (isHead) {
      const int k0 = ks * 28;
      float acc[8];
#pragma unroll
      for (int rr = 0; rr < 8; rr++) acc[rr] = 0.0f;
      const float* hh = h1gc + b;
#pragma unroll
      for (int k = k0; k < k0 + 28; k += 4) {
        float h0 = gload(&hh[(k + 0) * 32]), h1v = gload(&hh[(k + 1) * 32]);
        float h2 = gload(&hh[(k + 2) * 32]), h3  = gload(&hh[(k + 3) * 32]);
#pragma unroll
        for (int rr = 0; rr < 8; rr++) {
          const float4 wv = *(const float4*)&sm.wc2l[rr][k];
          acc[rr] = fmaf(wv.x, h0, fmaf(wv.y, h1v, fmaf(wv.z, h2, fmaf(wv.w, h3, acc[rr]))));
        }
      }
#pragma unroll
      for (int rr = 0; rr < 8; rr++) acc[rr] += __shfl_xor(acc[rr], 32);
      __syncthreads();
      if ((tid & 32) == 0) {
        int slot = ks >> 1;
#pragma unroll
        for (int rr = 0; rr < 8; rr++) sm.red[slot][rr][b] = acc[rr];
      }
      __syncthreads();
      if (tid < 256) {
        int rr = tid >> 5, bb = tid & 31;
        float s = bc2[w * 8 + rr];
#pragma unroll
        for (int kk = 0; kk < 8; kk++) s += sm.red[kk][rr][bb];
        sm.logit8[rr][bb] = s;
      }
      __syncthreads();
      if (tid < 32) {
        float bv = sm.logit8[0][tid]; int bi = 0;
#pragma unroll
        for (int rr = 1; rr < 8; rr++) {
          float x = sm.logit8[rr][tid];
          if (x > bv) { bv = x; bi = rr; }
        }
        u64t pack = ((u64t)f2ord(bv) << 32) | (u64t)(0xFFFFFFFFu - (unsigned)(w * 8 + bi));
        gmax64(&ncp[tid], pack);
      }
      asm volatile("s_waitcnt vmcnt(0)" ::: "memory");
      __syncthreads();
      if (tid == 0) __hip_atomic_fetch_add(&ctr[0], 1u, __ATOMIC_RELAXED, __HIP_MEMORY_SCOPE_AGENT);
    }
    pollctr(&ctr[0], 32u * (unsigned)(t + 1), dead);   // nc ready

    // ========== D: fine GRU (all WGs, j=2w,2w+1) ==========
    {
      if (tid < 32) {
        u64t p = gload64(&ncp[tid]);
        unsigned nc = 0xFFFFFFFFu - (unsigned)(p & 0xFFFFFFFFull);
        sm.sncn[tid] = (float)nc * (2.0f / 255.0f) - 1.0f;
        if (isHead && tid == w) out[(size_t)w * TSTEPS + t] = (float)nc;
      }
      __syncthreads();
      if (tid < 64) {
        int q = tid >> 5, bb = tid & 31;
        float sc = sm.scvo[bb], sf = sm.sfvo[bb], snc = sm.sncn[bb];
        float ipr = sm.wfil[q][0][0] * sc + sm.wfil[q][0][1] * sf + sm.wfil[q][0][2] * snc
                  + sm.condw[6 + q][tt][bb] + sm.bihl[6 + q];
        float ipu = sm.wfil[q][1][0] * sc + sm.wfil[q][1][1] * sf + sm.wfil[q][1][2] * snc
                  + sm.condw[8 + q][tt][bb] + sm.bihl[8 + q];
        float ipe = sm.wfil[q][2][0] * sc + sm.wfil[q][2][1] * sf + sm.wfil[q][2][2] * snc
                  + sm.condw[10 + q][tt][bb] + sm.bihl[10 + q];
        float r = sigm(sm.hpfl[0 + q][bb] + ipr);
        float u = sigm(sm.hpfl[2 + q][bb] + ipu);
        float e = tanhf(fmaf(r, sm.hpfl[4 + q][bb], ipe));
        float hnew = u * sm.fhid[q][bb] + (1.0f - u) * e;
        sm.fhid[q][bb] = hnew;
        gstore(&hcur[(size_t)(HALFN + 2 * w + q) * 32 + bb], hnew);
      }
      __syncthreads();
      if (tid < 32) sm.scvo[tid] = sm.sncn[tid];   // commit nc(t) as old coarse sample
    }
    gridbar(flags, ++ep, dead);                       // bar3: h_f ready

    // ========== E: FC1 fine (rows 2w,2w+1) ==========
    {
      const int k0 = ks * 28;
      float a0 = 0.0f, a1 = 0.0f;
      const float* hff = hcur + HALFN * 32 + b;
#pragma unroll
      for (int k = k0; k < k0 + 28; k += 4) {
        float h0 = gload(&hff[(k + 0) * 32]), h1v = gload(&hff[(k + 1) * 32]);
        float h2 = gload(&hff[(k + 2) * 32]), h3  = gload(&hff[(k + 3) * 32]);
        float4 v0 = *(const float4*)&sm.wf1l[0][k];
        a0 = fmaf(v0.x, h0, fmaf(v0.y, h1v, fmaf(v0.z, h2, fmaf(v0.w, h3, a0))));
        float4 v1 = *(const float4*)&sm.wf1l[1][k];
        a1 = fmaf(v1.x, h0, fmaf(v1.y, h1v, fmaf(v1.z, h2, fmaf(v1.w, h3, a1))));
      }
      a0 += __shfl_xor(a0, 32); a1 += __shfl_xor(a1, 32);
      __syncthreads();
      if ((tid & 32) == 0) { sm.red[ks >> 1][0][b] = a0; sm.red[ks >> 1][1][b] = a1; }
      if (isHead && tid == 256) gstore64(&ncp[w], 0ull);   // reset this step's pack
      __syncthreads();
      if (tid < 64) {
        int rr = tid >> 5, bb = tid & 31;
        float s = bf1[2 * w + rr];
#pragma unroll
        for (int kk = 0; kk < 8; kk++) s += sm.red[kk][rr][bb];
        gstore(&h1gf[(size_t)(2 * w + rr) * 32 + bb], fmaxf(s, 0.0f));
      }
    }
    gridbar(flags, ++ep, dead);                       // bar4: h1f ready

    // ========== F: FC2 fine (heads) — overlaps next step's GEMM ==========
    if (isHead) {
      const int k0 = ks * 28;
      float acc[8];
#pragma unroll
      for (int rr = 0; rr < 8; rr++) acc[rr] = 0.0f;
      const float* hh = h1gf + b;
#pragma unroll
      for (int k = k0; k < k0 + 28; k += 4) {
        float h0 = gload(&hh[(k + 0) * 32]), h1v = gload(&hh[(k + 1) * 32]);
        float h2 = gload(&hh[(k + 2) * 32]), h3  = gload(&hh[(k + 3) * 32]);
#pragma unroll
        for (int rr = 0; rr < 8; rr++) {
          const float4 wv = *(const float4*)&sm.wf2l[rr][k];
          acc[rr] = fmaf(wv.x, h0, fmaf(wv.y, h1v, fmaf(wv.z, h2, fmaf(wv.w, h3, acc[rr]))));
        }
      }
#pragma unroll
      for (int rr = 0; rr < 8; rr++) acc[rr] += __shfl_xor(acc[rr], 32);
      __syncthreads();
      if ((tid & 32) == 0) {
        int slot = ks >> 1;
#pragma unroll
        for (int rr = 0; rr < 8; rr++) sm.red[slot][rr][b] = acc[rr];
      }
      __syncthreads();
      if (tid < 256) {
        int rr = tid >> 5, bb = tid & 31;
        float s = bf2[w * 8 + rr];
#pragma unroll
        for (int kk = 0; kk < 8; kk++) s += sm.red[kk][rr][bb];
        sm.logit8[rr][bb] = s;
      }
      __syncthreads();
      if (tid < 32) {
        float bv = sm.logit8[0][tid]; int bi = 0;
#pragma unroll
        for (int rr = 1; rr < 8; rr++) {
          float x = sm.logit8[rr][tid];
          if (x > bv) { bv = x; bi = rr; }
        }
        u64t pack = ((u64t)f2ord(bv) << 32) | (u64t)(0xFFFFFFFFu - (unsigned)(w * 8 + bi));
        gmax64(&nfp[tid], pack);
      }
      asm volatile("s_waitcnt vmcnt(0)" ::: "memory");
      __syncthreads();
      if (tid == 0) __hip_atomic_fetch_add(&ctr[1], 1u, __ATOMIC_RELAXED, __HIP_MEMORY_SCOPE_AGENT);
    }
    // no barrier: non-heads already started next GEMM; nf consumed via poll in A
  }

  // ===== epilogue: nf(1023) + final hidden =====
  pollctr(&ctr[1], 32u * (unsigned)TSTEPS, dead);
  if (tid < 32 && isHead && tid == w) {
    u64t p = gload64(&nfp[tid]);
    unsigned nf = 0xFFFFFFFFu - (unsigned)(p & 0xFFFFFFFFull);
    out[32768 + (size_t)w * TSTEPS + (TSTEPS - 1)] = (float)nf;
  }
  if (tid < 64) {
    int q = tid >> 5, bb = tid & 31;
    out[65536 + (size_t)(2 * w + q) * 32 + bb]         = sm.chid[q][bb];
    out[65536 + (size_t)(HALFN + 2 * w + q) * 32 + bb] = sm.fhid[q][bb];
  }
}

extern "C" void kernel_launch(void* const* d_in, const int* in_sizes, int n_in,
                              void* d_out, int out_size, void* d_ws, size_t ws_size,
                              hipStream_t stream) {
  const float* cond = (const float*)d_in[0];
  const float* wci  = (const float*)d_in[1];
  const float* wfi  = (const float*)d_in[2];
  const float* whh  = (const float*)d_in[3];
  const float* bih  = (const float*)d_in[4];
  const float* bhh  = (const float*)d_in[5];
  const float* wc1  = (const float*)d_in[6];
  const float* bc1  = (const float*)d_in[7];
  const float* wc2  = (const float*)d_in[8];
  const float* bc2  = (const float*)d_in[9];
  const float* wf1  = (const float*)d_in[10];
  const float* bf1  = (const float*)d_in[11];
  const float* wf2  = (const float*)d_in[12];
  const float* bf2  = (const float*)d_in[13];
  float* out = (float*)d_out;
  float* ws  = (float*)d_ws;

  hipLaunchKernelGGL(wavernn_init, dim3(64), dim3(256), 0, stream, ws);
  hipLaunchKernelGGL(wavernn_persist, dim3(NWG), dim3(NTHR), 0, stream,
                     cond, wci, wfi, whh, bih, bhh,
                     wc1, bc1, wc2, bc2, wf1, bf1, wf2, bf2, out, ws);
}